// Round 18
// baseline (185.578 us; speedup 1.0000x reference)
//
#include <hip/hip_runtime.h>
#include <hip/hip_bf16.h>

#define NN 100000
#define FIN 128
#define H8 64      // heads*hid = 8*8
#define NC 16
#define BKS 9      // bucket shift: 512 nodes/bucket
#define BMASK 511
#define CHUNK 8192 // edges per binning block

typedef unsigned short ushort_t;
typedef unsigned int uint_t;

__device__ __forceinline__ float bu2f(ushort_t u) {
    unsigned v = ((unsigned)u) << 16;
    return __uint_as_float(v);
}
__device__ __forceinline__ ushort_t f2bu(float f) {
    __hip_bfloat16 h = __float2bfloat16(f);
    return *reinterpret_cast<ushort_t*>(&h);
}
__device__ __forceinline__ float dot4(float4 a, float4 b) {
    return a.x * b.x + a.y * b.y + a.z * b.z + a.w * b.w;
}
__device__ __forceinline__ void fma4(float4& a, float s, float4 w) {
    a.x += s * w.x; a.y += s * w.y; a.z += s * w.z; a.w += s * w.w;
}

// ---------------- device bodies (for fused launches) ----------------

// gemm1 body: block gb handles nodes [gb*64, gb*64+64); ws = 32KB LDS arena
__device__ __forceinline__ void gemm1_body(int gb,
        const float* __restrict__ x, const float* __restrict__ W,
        const float* __restrict__ attS, const float* __restrict__ attD,
        ushort_t* __restrict__ h1b, float* __restrict__ as1,
        float* __restrict__ ad1, int n, float* ws) {
    int t = threadIdx.x;
    const float4* W4 = (const float4*)W;
    float4* ws4 = (float4*)ws;
    for (int j = t; j < FIN * H8 / 4; j += 256) ws4[j] = W4[j];
    __syncthreads();

    int wv = t >> 6, lane = t & 63;
    int ng = lane >> 4, cg = lane & 15;
    int node0 = (gb * 4 + wv) * 16 + ng * 4;

    int r0 = min(node0 + 0, n - 1), r1 = min(node0 + 1, n - 1);
    int r2 = min(node0 + 2, n - 1), r3 = min(node0 + 3, n - 1);
    const float* xp0 = x + (long)r0 * FIN;
    const float* xp1 = x + (long)r1 * FIN;
    const float* xp2 = x + (long)r2 * FIN;
    const float* xp3 = x + (long)r3 * FIN;

    float4 a0 = {0, 0, 0, 0}, a1 = {0, 0, 0, 0}, a2 = {0, 0, 0, 0}, a3 = {0, 0, 0, 0};
#pragma unroll 2
    for (int k = 0; k < FIN; k += 4) {
        float4 xa = *(const float4*)(xp0 + k);
        float4 xb = *(const float4*)(xp1 + k);
        float4 xc = *(const float4*)(xp2 + k);
        float4 xd = *(const float4*)(xp3 + k);
        float4 w0 = *(const float4*)(ws + (k + 0) * H8 + cg * 4);
        float4 w1 = *(const float4*)(ws + (k + 1) * H8 + cg * 4);
        float4 w2 = *(const float4*)(ws + (k + 2) * H8 + cg * 4);
        float4 w3 = *(const float4*)(ws + (k + 3) * H8 + cg * 4);
        fma4(a0, xa.x, w0); fma4(a0, xa.y, w1); fma4(a0, xa.z, w2); fma4(a0, xa.w, w3);
        fma4(a1, xb.x, w0); fma4(a1, xb.y, w1); fma4(a1, xb.z, w2); fma4(a1, xb.w, w3);
        fma4(a2, xc.x, w0); fma4(a2, xc.y, w1); fma4(a2, xc.z, w2); fma4(a2, xc.w, w3);
        fma4(a3, xd.x, w0); fma4(a3, xd.y, w1); fma4(a3, xd.z, w2); fma4(a3, xd.w, w3);
    }

    float4 sA = *(const float4*)(attS + cg * 4);
    float4 dA = *(const float4*)(attD + cg * 4);
    float4 av[4] = {a0, a1, a2, a3};
#pragma unroll
    for (int j = 0; j < 4; ++j) {
        int node = node0 + j;
        float4 a = av[j];
        float vs = dot4(a, sA);
        float vd = dot4(a, dA);
        vs += __shfl_xor(vs, 1, 64);
        vd += __shfl_xor(vd, 1, 64);
        if (node < n) {
            ushort4 q;
            q.x = f2bu(a.x); q.y = f2bu(a.y); q.z = f2bu(a.z); q.w = f2bu(a.w);
            *(ushort4*)(h1b + (long)node * H8 + cg * 4) = q;
            if ((lane & 1) == 0) {
                as1[node * 8 + (cg >> 1)] = vs;
                ad1[node * 8 + (cg >> 1)] = vd;
            }
        }
    }
}

// binA body: histogram for CSR block cb, transposed store
__device__ __forceinline__ void binA_body(int cb, const int* __restrict__ dst,
        int* __restrict__ bh, int e, int nb, int nblk, int* hist) {
    int t = threadIdx.x;
    hist[t] = 0;
    __syncthreads();
    int base = cb * CHUNK;
    int endj = min(base + CHUNK, e);
    for (int k0 = base + t * 4; k0 < endj; k0 += 1024) {
        if (k0 + 3 < endj) {
            int4 d4 = *(const int4*)(dst + k0);
            atomicAdd(&hist[d4.x >> BKS], 1);
            atomicAdd(&hist[d4.y >> BKS], 1);
            atomicAdd(&hist[d4.z >> BKS], 1);
            atomicAdd(&hist[d4.w >> BKS], 1);
        } else {
            for (int k = k0; k < endj; ++k) atomicAdd(&hist[dst[k] >> BKS], 1);
        }
    }
    __syncthreads();
    if (t < nb) bh[t * nblk + cb] = hist[t];
}

// scanB body: bucket j scans its per-block counts
__device__ __forceinline__ void scanB_body(int j, int* __restrict__ bh,
        int* __restrict__ btot, int nblk, int* ts) {
    int t = threadIdx.x;
    int v = (t < nblk) ? bh[j * nblk + t] : 0;
    ts[t] = v;
    __syncthreads();
    int run = v;
    for (int off = 1; off < 256; off <<= 1) {
        int y = (t >= off) ? ts[t - off] : 0;
        __syncthreads();
        run += y;
        ts[t] = run;
        __syncthreads();
    }
    if (t < nblk) bh[j * nblk + t] = run - v;
    if (t == 255) btot[j] = run;
}

// binC body: scatter packed entries for CSR block cb
__device__ __forceinline__ void binC_body(int cb, const int* __restrict__ src,
        const int* __restrict__ dst, const int* __restrict__ bh,
        const int* __restrict__ bstart, uint_t* __restrict__ binned,
        int e, int nb, int nblk, int* off) {
    int t = threadIdx.x;
    if (t < nb) off[t] = bh[t * nblk + cb] + bstart[t];
    __syncthreads();
    int base = cb * CHUNK;
    int endj = min(base + CHUNK, e);
    for (int k0 = base + t * 4; k0 < endj; k0 += 1024) {
        if (k0 + 3 < endj) {
            int4 d4 = *(const int4*)(dst + k0);
            int4 s4 = *(const int4*)(src + k0);
            int p0 = atomicAdd(&off[d4.x >> BKS], 1);
            binned[p0] = ((uint_t)(d4.x & BMASK) << 17) | (uint_t)s4.x;
            int p1 = atomicAdd(&off[d4.y >> BKS], 1);
            binned[p1] = ((uint_t)(d4.y & BMASK) << 17) | (uint_t)s4.y;
            int p2 = atomicAdd(&off[d4.z >> BKS], 1);
            binned[p2] = ((uint_t)(d4.z & BMASK) << 17) | (uint_t)s4.z;
            int p3 = atomicAdd(&off[d4.w >> BKS], 1);
            binned[p3] = ((uint_t)(d4.w & BMASK) << 17) | (uint_t)s4.w;
        } else {
            for (int k = k0; k < endj; ++k) {
                int d = dst[k], s = src[k];
                int p = atomicAdd(&off[d >> BKS], 1);
                binned[p] = ((uint_t)(d & BMASK) << 17) | (uint_t)s;
            }
        }
    }
}

// ---------------- fused launches: CSR stage ∥ gemm1 slice ----------------

__global__ __launch_bounds__(256) void k_fuseA(const int* __restrict__ dst,
        int* __restrict__ bh, int e, int nb, int nblk,
        const float* __restrict__ x, const float* __restrict__ W,
        const float* __restrict__ attS, const float* __restrict__ attD,
        ushort_t* __restrict__ h1b, float* __restrict__ as1,
        float* __restrict__ ad1, int n) {
    __shared__ float smem[FIN * H8];   // 32 KB arena
    if ((int)blockIdx.x < nblk)
        binA_body(blockIdx.x, dst, bh, e, nb, nblk, (int*)smem);
    else
        gemm1_body(blockIdx.x - nblk, x, W, attS, attD, h1b, as1, ad1, n, smem);
}

__global__ __launch_bounds__(256) void k_fuseB(int* __restrict__ bh,
        int* __restrict__ btot, int nblk, int nb, int g1ofs,
        const float* __restrict__ x, const float* __restrict__ W,
        const float* __restrict__ attS, const float* __restrict__ attD,
        ushort_t* __restrict__ h1b, float* __restrict__ as1,
        float* __restrict__ ad1, int n) {
    __shared__ float smem[FIN * H8];
    if ((int)blockIdx.x < nb)
        scanB_body(blockIdx.x, bh, btot, nblk, (int*)smem);
    else
        gemm1_body(g1ofs + blockIdx.x - nb, x, W, attS, attD, h1b, as1, ad1, n, smem);
}

__global__ __launch_bounds__(256) void k_fuseC(const int* __restrict__ src,
        const int* __restrict__ dst, const int* __restrict__ bh,
        const int* __restrict__ bstart, uint_t* __restrict__ binned,
        int e, int nb, int nblk, int g1ofs,
        const float* __restrict__ x, const float* __restrict__ W,
        const float* __restrict__ attS, const float* __restrict__ attD,
        ushort_t* __restrict__ h1b, float* __restrict__ as1,
        float* __restrict__ ad1, int n) {
    __shared__ float smem[FIN * H8];
    if ((int)blockIdx.x < nblk)
        binC_body(blockIdx.x, src, dst, bh, bstart, binned, e, nb, nblk, (int*)smem);
    else
        gemm1_body(g1ofs + blockIdx.x - nblk, x, W, attS, attD, h1b, as1, ad1, n, smem);
}

// Scan of bucket totals -> bstart[0..nb]
__global__ __launch_bounds__(256) void k_scanT(const int* __restrict__ btot,
        int* __restrict__ bstart, int nb) {
    __shared__ int ts[256];
    int j = threadIdx.x;
    int s = (j < nb) ? btot[j] : 0;
    ts[j] = s;
    __syncthreads();
    int run = s;
    for (int off = 1; off < 256; off <<= 1) {
        int y = (j >= off) ? ts[j - off] : 0;
        __syncthreads();
        run += y;
        ts[j] = run;
        __syncthreads();
    }
    if (j < nb) bstart[j] = run - s;
    if (j == nb - 1) bstart[nb] = run;
}

// Fused per-bucket CSR finalize: degree hist + scan + selfloop + scatter.
__global__ __launch_bounds__(256) void k_bucket(const uint_t* __restrict__ binned,
        const int* __restrict__ bstart, int* __restrict__ rp, int* __restrict__ col,
        int e, int n, int nb) {
    __shared__ int deg[512];
    __shared__ int ts[256];
    int b = blockIdx.x, t = threadIdx.x;
    int node0 = b << BKS;
    int S = bstart[b];
    int Se = bstart[b + 1];
    deg[t] = 0; deg[t + 256] = 0;
    __syncthreads();
    for (int k = S + t; k < Se; k += 256)
        atomicAdd(&deg[binned[k] >> 17], 1);
    __syncthreads();
    int g0 = node0 + 2 * t, g1 = g0 + 1;
    int c0 = (g0 < n) ? deg[2 * t] + 1 : 0;      // +1 = self-loop
    int c1 = (g1 < n) ? deg[2 * t + 1] + 1 : 0;
    int s = c0 + c1;
    ts[t] = s;
    __syncthreads();
    int run = s;
    for (int off = 1; off < 256; off <<= 1) {
        int y = (t >= off) ? ts[t - off] : 0;
        __syncthreads();
        run += y;
        ts[t] = run;
        __syncthreads();
    }
    int ex = run - s;
    int base = S + node0;
    int p0 = base + ex, p1 = base + ex + c0;
    if (g0 < n) { rp[g0] = p0; col[p0] = g0; deg[2 * t] = p0 + 1; }
    if (g1 < n) { rp[g1] = p1; col[p1] = g1; deg[2 * t + 1] = p1 + 1; }
    if (b == nb - 1 && t == 0) rp[n] = e + n;
    __syncthreads();
    for (int k = S + t; k < Se; k += 256) {
        uint_t pk = binned[k];
        int dLow = pk >> 17;
        int sv = (int)(pk & 0x1FFFFu);
        int p = atomicAdd(&deg[dLow], 1);
        col[p] = sv;
    }
}

// ------- Layer 1 aggregation + bias + ReLU + FUSED layer-2 matvec -------
// TWO nodes per wave. Main loop identical to r15. Epilogue: z stays in
// registers; h2 = z @ W2 (LDS, pad 17), att dots vs LDS attS2/attD2;
// writes h2b (bf16) + as2/ad2 directly. No z1b round-trip, no gemm2 kernel.

__global__ __launch_bounds__(256) void k_agg1(const int* __restrict__ rp,
        const int* __restrict__ col, const ushort_t* __restrict__ h1b,
        const float* __restrict__ as1, const float* __restrict__ ad1,
        const float* __restrict__ b1, const float* __restrict__ W2,
        const float* __restrict__ attS2, const float* __restrict__ attD2,
        ushort_t* __restrict__ h2b, float* __restrict__ as2,
        float* __restrict__ ad2, int n) {
    __shared__ float w2s[H8 * 17];   // [64][17] padded
    __shared__ float s2s[NC], d2s[NC];
    {
        int t = threadIdx.x;
        for (int j = t; j < H8 * NC; j += 256) {
            int ch = j >> 4, c = j & 15;
            w2s[ch * 17 + c] = W2[j];
        }
        if (t < NC) { s2s[t] = attS2[t]; d2s[t] = attD2[t]; }
    }
    __syncthreads();

    int w = (blockIdx.x * 256 + threadIdx.x) >> 6;
    int lane = threadIdx.x & 63;
    int iA = w * 2, iB = iA + 1;
    if (iA >= n) return;
    bool hasB = (iB < n);
    int slot = lane >> 3;   // edge sub-index (0..7)
    int h2 = lane & 7;      // head; channels h2*8 .. h2*8+7
    int l16 = lane & 15;
    int begA = rp[iA], endA = rp[iA + 1];
    int begB = hasB ? rp[iB] : 0, endB = hasB ? rp[iB + 1] : 0;
    int lastA = endA - 1, lastB = endB - 1;
    float adiA = ad1[iA * 8 + h2];
    float adiB = hasB ? ad1[iB * 8 + h2] : 0.f;
    float denA = 0.f, denB = 0.f;
    float numA[8] = {0.f, 0.f, 0.f, 0.f, 0.f, 0.f, 0.f, 0.f};
    float numB[8] = {0.f, 0.f, 0.f, 0.f, 0.f, 0.f, 0.f, 0.f};
    int roundsA = (endA - begA + 15) >> 4;
    int roundsB = hasB ? ((endB - begB + 15) >> 4) : 0;
    int rmax = max(roundsA, roundsB);
    int vA = col[min(begA + l16, lastA)];
    int vB = roundsB ? col[min(begB + l16, lastB)] : 0;
    for (int r = 0; r < rmax; ++r) {
        bool mA = r < roundsA, mB = r < roundsB;   // wave-uniform
        int kA0 = begA + r * 16, kB0 = begB + r * 16;
        int vnA = 0, vnB = 0;
        if (r + 1 < roundsA) vnA = col[min(kA0 + 16 + l16, lastA)];
        if (r + 1 < roundsB) vnB = col[min(kB0 + 16 + l16, lastB)];
        float pAa = 0.f, pAb = 0.f, pBa = 0.f, pBb = 0.f;
        uint4 uaA, ubA, uaB, ubB;
        if (mA) {
            int s0 = __shfl(vA, slot, 64);
            int s1 = __shfl(vA, 8 + slot, 64);
            float sv0 = as1[s0 * 8 + h2];
            float sv1 = as1[s1 * 8 + h2];
            uaA = *((const uint4*)(h1b + ((size_t)(unsigned)s0 << 6)) + h2);
            ubA = *((const uint4*)(h1b + ((size_t)(unsigned)s1 << 6)) + h2);
            float e0 = sv0 + adiA;
            e0 = fmaxf(e0, 0.f) + 0.2f * fminf(e0, 0.f);
            pAa = (kA0 + slot < endA) ? __expf(e0) : 0.f;
            float e1 = sv1 + adiA;
            e1 = fmaxf(e1, 0.f) + 0.2f * fminf(e1, 0.f);
            pAb = (kA0 + 8 + slot < endA) ? __expf(e1) : 0.f;
            denA += pAa + pAb;
        }
        if (mB) {
            int s0 = __shfl(vB, slot, 64);
            int s1 = __shfl(vB, 8 + slot, 64);
            float sv0 = as1[s0 * 8 + h2];
            float sv1 = as1[s1 * 8 + h2];
            uaB = *((const uint4*)(h1b + ((size_t)(unsigned)s0 << 6)) + h2);
            ubB = *((const uint4*)(h1b + ((size_t)(unsigned)s1 << 6)) + h2);
            float e0 = sv0 + adiB;
            e0 = fmaxf(e0, 0.f) + 0.2f * fminf(e0, 0.f);
            pBa = (kB0 + slot < endB) ? __expf(e0) : 0.f;
            float e1 = sv1 + adiB;
            e1 = fmaxf(e1, 0.f) + 0.2f * fminf(e1, 0.f);
            pBb = (kB0 + 8 + slot < endB) ? __expf(e1) : 0.f;
            denB += pBa + pBb;
        }
#define ACC8(NUM, P, U)                                                    \
        {                                                                  \
            NUM[0] += (P) * __uint_as_float((U).x << 16);                  \
            NUM[1] += (P) * __uint_as_float((U).x & 0xffff0000u);          \
            NUM[2] += (P) * __uint_as_float((U).y << 16);                  \
            NUM[3] += (P) * __uint_as_float((U).y & 0xffff0000u);          \
            NUM[4] += (P) * __uint_as_float((U).z << 16);                  \
            NUM[5] += (P) * __uint_as_float((U).z & 0xffff0000u);          \
            NUM[6] += (P) * __uint_as_float((U).w << 16);                  \
            NUM[7] += (P) * __uint_as_float((U).w & 0xffff0000u);          \
        }
        if (mA) { ACC8(numA, pAa, uaA) ACC8(numA, pAb, ubA) }
        if (mB) { ACC8(numB, pBa, uaB) ACC8(numB, pBb, ubB) }
#undef ACC8
        vA = vnA; vB = vnB;
    }
    // reduce over slot bits (3,4,5); head stays = lane&7
#pragma unroll
    for (int q = 0; q < 8; ++q) {
        numA[q] += __shfl_xor(numA[q], 8, 64);
        numA[q] += __shfl_xor(numA[q], 16, 64);
        numA[q] += __shfl_xor(numA[q], 32, 64);
        numB[q] += __shfl_xor(numB[q], 8, 64);
        numB[q] += __shfl_xor(numB[q], 16, 64);
        numB[q] += __shfl_xor(numB[q], 32, 64);
    }
    denA += __shfl_xor(denA, 8, 64);
    denA += __shfl_xor(denA, 16, 64);
    denA += __shfl_xor(denA, 32, 64);
    denB += __shfl_xor(denB, 8, 64);
    denB += __shfl_xor(denB, 16, 64);
    denB += __shfl_xor(denB, 32, 64);
    // z = relu(num/den + b1) in registers (replicated across slot groups)
    float invdA = 1.0f / (denA + 1e-16f);
    float invdB = 1.0f / (denB + 1e-16f);
    float4 bb0 = *(const float4*)(b1 + h2 * 8);
    float4 bb1 = *(const float4*)(b1 + h2 * 8 + 4);
    float zA[8], zB[8];
    zA[0] = fmaxf(numA[0] * invdA + bb0.x, 0.f);
    zA[1] = fmaxf(numA[1] * invdA + bb0.y, 0.f);
    zA[2] = fmaxf(numA[2] * invdA + bb0.z, 0.f);
    zA[3] = fmaxf(numA[3] * invdA + bb0.w, 0.f);
    zA[4] = fmaxf(numA[4] * invdA + bb1.x, 0.f);
    zA[5] = fmaxf(numA[5] * invdA + bb1.y, 0.f);
    zA[6] = fmaxf(numA[6] * invdA + bb1.z, 0.f);
    zA[7] = fmaxf(numA[7] * invdA + bb1.w, 0.f);
    zB[0] = fmaxf(numB[0] * invdB + bb0.x, 0.f);
    zB[1] = fmaxf(numB[1] * invdB + bb0.y, 0.f);
    zB[2] = fmaxf(numB[2] * invdB + bb0.z, 0.f);
    zB[3] = fmaxf(numB[3] * invdB + bb0.w, 0.f);
    zB[4] = fmaxf(numB[4] * invdB + bb1.x, 0.f);
    zB[5] = fmaxf(numB[5] * invdB + bb1.y, 0.f);
    zB[6] = fmaxf(numB[6] * invdB + bb1.z, 0.f);
    zB[7] = fmaxf(numB[7] * invdB + bb1.w, 0.f);
    // fused gemm2: lane (slot,h2) computes classes c0,c1 partials over its 8 ch
    int c0 = slot * 2, c1 = c0 + 1;
    float pA0 = 0.f, pA1 = 0.f, pB0 = 0.f, pB1 = 0.f;
#pragma unroll
    for (int j = 0; j < 8; ++j) {
        int ch = h2 * 8 + j;
        float w0 = w2s[ch * 17 + c0];
        float w1 = w2s[ch * 17 + c1];
        pA0 += zA[j] * w0; pA1 += zA[j] * w1;
        pB0 += zB[j] * w0; pB1 += zB[j] * w1;
    }
    // reduce over h2 bits (0,1,2) -> full h2[c0],h2[c1] replicated
    pA0 += __shfl_xor(pA0, 1, 64); pA0 += __shfl_xor(pA0, 2, 64); pA0 += __shfl_xor(pA0, 4, 64);
    pA1 += __shfl_xor(pA1, 1, 64); pA1 += __shfl_xor(pA1, 2, 64); pA1 += __shfl_xor(pA1, 4, 64);
    pB0 += __shfl_xor(pB0, 1, 64); pB0 += __shfl_xor(pB0, 2, 64); pB0 += __shfl_xor(pB0, 4, 64);
    pB1 += __shfl_xor(pB1, 1, 64); pB1 += __shfl_xor(pB1, 2, 64); pB1 += __shfl_xor(pB1, 4, 64);
    // att dots: partial per slot group, reduce over slot bits
    float vsA = pA0 * s2s[c0] + pA1 * s2s[c1];
    float vdA = pA0 * d2s[c0] + pA1 * d2s[c1];
    float vsB = pB0 * s2s[c0] + pB1 * s2s[c1];
    float vdB = pB0 * d2s[c0] + pB1 * d2s[c1];
    vsA += __shfl_xor(vsA, 8, 64); vsA += __shfl_xor(vsA, 16, 64); vsA += __shfl_xor(vsA, 32, 64);
    vdA += __shfl_xor(vdA, 8, 64); vdA += __shfl_xor(vdA, 16, 64); vdA += __shfl_xor(vdA, 32, 64);
    vsB += __shfl_xor(vsB, 8, 64); vsB += __shfl_xor(vsB, 16, 64); vsB += __shfl_xor(vsB, 32, 64);
    vdB += __shfl_xor(vdB, 8, 64); vdB += __shfl_xor(vdB, 16, 64); vdB += __shfl_xor(vdB, 32, 64);
    // stores
    if (h2 == 0) {
        uint_t qw = (uint_t)f2bu(pA0) | ((uint_t)f2bu(pA1) << 16);
        ((uint_t*)(h2b + (size_t)iA * NC))[slot] = qw;
    } else if (h2 == 1 && hasB) {
        uint_t qw = (uint_t)f2bu(pB0) | ((uint_t)f2bu(pB1) << 16);
        ((uint_t*)(h2b + (size_t)iB * NC))[slot] = qw;
    }
    if (lane == 0) { as2[iA] = vsA; ad2[iA] = vdA; }
    if (lane == 1 && hasB) { as2[iB] = vsB; ad2[iB] = vdB; }
}

// ---------------- Layer 2 aggregation + bias + log_softmax ----------------

__global__ __launch_bounds__(256) void k_agg2(const int* __restrict__ rp,
        const int* __restrict__ col, const ushort_t* __restrict__ h2b,
        const float* __restrict__ as2, const float* __restrict__ ad2,
        const float* __restrict__ b2, float* __restrict__ out, int n) {
    int i = (blockIdx.x * 256 + threadIdx.x) >> 6;
    int lane = threadIdx.x & 63;
    if (i >= n) return;
    int grp = lane >> 3;    // edge group (0..7)
    int cp = lane & 7;      // channel pair: ch 2cp, 2cp+1
    int beg = rp[i], end = rp[i + 1];
    int last = end - 1;
    int deg = end - beg;
    float adi = ad2[i];
    const uint_t* h2u = (const uint_t*)h2b;
    float denp = 0.f, nx = 0.f, ny = 0.f;
    int rounds = (deg + 31) >> 5;
    for (int r = 0; r < rounds; ++r) {
        int k = beg + r * 32;
        int rem = end - k;               // wave-uniform, > 0
        int v = col[min(k + (lane & 31), last)];
        float sv = as2[v];
        float e = sv + adi;
        e = fmaxf(e, 0.f) + 0.2f * fminf(e, 0.f);
        int lim = min(rem, 32);
        float p = (lane < lim) ? __expf(e) : 0.f;
        denp += p;
#define AGG2_PAIR(S0, S1)                                                  \
        {                                                                  \
            int i0 = (S0) * 8 + grp, i1 = (S1) * 8 + grp;                  \
            int r0 = __shfl(v, i0, 64), r1 = __shfl(v, i1, 64);            \
            float q0 = __shfl(p, i0, 64), q1 = __shfl(p, i1, 64);          \
            uint_t u0 = h2u[((size_t)(unsigned)r0 << 3) + cp];             \
            uint_t u1 = h2u[((size_t)(unsigned)r1 << 3) + cp];             \
            nx += q0 * __uint_as_float(u0 << 16);                          \
            ny += q0 * __uint_as_float(u0 & 0xffff0000u);                  \
            nx += q1 * __uint_as_float(u1 << 16);                          \
            ny += q1 * __uint_as_float(u1 & 0xffff0000u);                  \
        }
        AGG2_PAIR(0, 1)
        if (lim > 16) AGG2_PAIR(2, 3)
#undef AGG2_PAIR
    }
    nx += __shfl_xor(nx, 8, 64);  ny += __shfl_xor(ny, 8, 64);
    nx += __shfl_xor(nx, 16, 64); ny += __shfl_xor(ny, 16, 64);
    nx += __shfl_xor(nx, 32, 64); ny += __shfl_xor(ny, 32, 64);
    denp += __shfl_xor(denp, 1, 64);
    denp += __shfl_xor(denp, 2, 64);
    denp += __shfl_xor(denp, 4, 64);
    denp += __shfl_xor(denp, 8, 64);
    denp += __shfl_xor(denp, 16, 64);
    denp += __shfl_xor(denp, 32, 64);
    float invd = 1.0f / (denp + 1e-16f);
    float2 bp = ((const float2*)b2)[cp];
    float ox = nx * invd + bp.x;
    float oy = ny * invd + bp.y;
    float mx = fmaxf(ox, oy);
    mx = fmaxf(mx, __shfl_xor(mx, 1, 64));
    mx = fmaxf(mx, __shfl_xor(mx, 2, 64));
    mx = fmaxf(mx, __shfl_xor(mx, 4, 64));
    float sm = __expf(ox - mx) + __expf(oy - mx);
    sm += __shfl_xor(sm, 1, 64);
    sm += __shfl_xor(sm, 2, 64);
    sm += __shfl_xor(sm, 4, 64);
    float lg = mx + __logf(sm);
    if (lane < 8) {
        float2 res = {ox - lg, oy - lg};
        ((float2*)(out + (size_t)i * NC))[cp] = res;
    }
}

// ---------------- launcher ----------------

extern "C" void kernel_launch(void* const* d_in, const int* in_sizes, int n_in,
                              void* d_out, int out_size, void* d_ws, size_t ws_size,
                              hipStream_t stream) {
    const float* x     = (const float*)d_in[0];
    const int*   ei    = (const int*)d_in[1];
    const float* W1    = (const float*)d_in[2];
    const float* attS1 = (const float*)d_in[3];
    const float* attD1 = (const float*)d_in[4];
    const float* b1    = (const float*)d_in[5];
    const float* W2    = (const float*)d_in[6];
    const float* attS2 = (const float*)d_in[7];
    const float* attD2 = (const float*)d_in[8];
    const float* b2    = (const float*)d_in[9];
    float* out = (float*)d_out;

    const int N = NN;
    const int E = in_sizes[1] / 2;
    const int NB = (N + (1 << BKS) - 1) >> BKS;      // buckets (196)
    const int NBLK = (E + CHUNK - 1) / CHUNK;        // binning blocks (196)

    ushort_t* z1b = (ushort_t*)d_ws;            // scratch (binned alias)
    float* as1 = (float*)(z1b + (size_t)N * H8);// N*8
    float* ad1 = as1 + (size_t)N * 8;           // N*8
    float* as2 = ad1 + (size_t)N * 8;           // N
    float* ad2 = as2 + N;                       // N
    ushort_t* h1b = (ushort_t*)(ad2 + N);       // N*64 bf16
    ushort_t* h2b = h1b + (size_t)N * H8;       // N*16 bf16
    int* rp   = (int*)(h2b + (size_t)N * NC);   // N+1
    int* col  = rp + (N + 1);                   // E+N
    int* bh   = col + (E + N);                  // NB*NBLK (bucket-major)
    int* btot = bh + (size_t)NB * NBLK;         // NB
    int* bstart = btot + NB;                    // NB+1
    uint_t* binned = (uint_t*)z1b;              // E * 4B

    const int* srcp = ei;
    const int* dstp = ei + E;

    const int G1 = (N + 63) / 64;               // total gemm1 blocks (1563)
    const int G1A = G1 * 1 / 3;
    const int G1B = G1 * 1 / 3;
    const int G1C = G1 - G1A - G1B;

    k_fuseA<<<NBLK + G1A, 256, 0, stream>>>(dstp, bh, E, NB, NBLK,
            x, W1, attS1, attD1, h1b, as1, ad1, N);
    k_fuseB<<<NB + G1B, 256, 0, stream>>>(bh, btot, NBLK, NB, G1A,
            x, W1, attS1, attD1, h1b, as1, ad1, N);
    k_scanT<<<1, 256, 0, stream>>>(btot, bstart, NB);
    k_fuseC<<<NBLK + G1C, 256, 0, stream>>>(srcp, dstp, bh, bstart, binned,
            E, NB, NBLK, G1A + G1B, x, W1, attS1, attD1, h1b, as1, ad1, N);
    k_bucket<<<NB, 256, 0, stream>>>(binned, bstart, rp, col, E, N, NB);

    k_agg1<<<(N + 7) / 8, 256, 0, stream>>>(rp, col, h1b, as1, ad1, b1,
            W2, attS2, attD2, h2b, as2, ad2, N);
    k_agg2<<<(N + 3) / 4, 256, 0, stream>>>(rp, col, h2b, as2, ad2, b2, out, N);
}

// Round 19
// 180.055 us; speedup vs baseline: 1.0307x; 1.0307x over previous
//
#include <hip/hip_runtime.h>
#include <hip/hip_bf16.h>

#define NN 100000
#define FIN 128
#define H8 64      // heads*hid = 8*8
#define NC 16
#define BKS 9      // bucket shift: 512 nodes/bucket
#define BMASK 511
#define CHUNK 8192 // edges per binning block

typedef unsigned short ushort_t;
typedef unsigned int uint_t;

__device__ __forceinline__ float bu2f(ushort_t u) {
    unsigned v = ((unsigned)u) << 16;
    return __uint_as_float(v);
}
__device__ __forceinline__ ushort_t f2bu(float f) {
    __hip_bfloat16 h = __float2bfloat16(f);
    return *reinterpret_cast<ushort_t*>(&h);
}
__device__ __forceinline__ float dot4(float4 a, float4 b) {
    return a.x * b.x + a.y * b.y + a.z * b.z + a.w * b.w;
}
__device__ __forceinline__ void fma4(float4& a, float s, float4 w) {
    a.x += s * w.x; a.y += s * w.y; a.z += s * w.z; a.w += s * w.w;
}

// ---------------- device bodies (for fused launches) ----------------

// gemm1 body: block gb handles nodes [gb*64, gb*64+64); ws = 32KB LDS arena
__device__ __forceinline__ void gemm1_body(int gb,
        const float* __restrict__ x, const float* __restrict__ W,
        const float* __restrict__ attS, const float* __restrict__ attD,
        ushort_t* __restrict__ h1b, float* __restrict__ as1,
        float* __restrict__ ad1, int n, float* ws) {
    int t = threadIdx.x;
    const float4* W4 = (const float4*)W;
    float4* ws4 = (float4*)ws;
    for (int j = t; j < FIN * H8 / 4; j += 256) ws4[j] = W4[j];
    __syncthreads();

    int wv = t >> 6, lane = t & 63;
    int ng = lane >> 4, cg = lane & 15;
    int node0 = (gb * 4 + wv) * 16 + ng * 4;

    int r0 = min(node0 + 0, n - 1), r1 = min(node0 + 1, n - 1);
    int r2 = min(node0 + 2, n - 1), r3 = min(node0 + 3, n - 1);
    const float* xp0 = x + (long)r0 * FIN;
    const float* xp1 = x + (long)r1 * FIN;
    const float* xp2 = x + (long)r2 * FIN;
    const float* xp3 = x + (long)r3 * FIN;

    float4 a0 = {0, 0, 0, 0}, a1 = {0, 0, 0, 0}, a2 = {0, 0, 0, 0}, a3 = {0, 0, 0, 0};
#pragma unroll 2
    for (int k = 0; k < FIN; k += 4) {
        float4 xa = *(const float4*)(xp0 + k);
        float4 xb = *(const float4*)(xp1 + k);
        float4 xc = *(const float4*)(xp2 + k);
        float4 xd = *(const float4*)(xp3 + k);
        float4 w0 = *(const float4*)(ws + (k + 0) * H8 + cg * 4);
        float4 w1 = *(const float4*)(ws + (k + 1) * H8 + cg * 4);
        float4 w2 = *(const float4*)(ws + (k + 2) * H8 + cg * 4);
        float4 w3 = *(const float4*)(ws + (k + 3) * H8 + cg * 4);
        fma4(a0, xa.x, w0); fma4(a0, xa.y, w1); fma4(a0, xa.z, w2); fma4(a0, xa.w, w3);
        fma4(a1, xb.x, w0); fma4(a1, xb.y, w1); fma4(a1, xb.z, w2); fma4(a1, xb.w, w3);
        fma4(a2, xc.x, w0); fma4(a2, xc.y, w1); fma4(a2, xc.z, w2); fma4(a2, xc.w, w3);
        fma4(a3, xd.x, w0); fma4(a3, xd.y, w1); fma4(a3, xd.z, w2); fma4(a3, xd.w, w3);
    }

    float4 sA = *(const float4*)(attS + cg * 4);
    float4 dA = *(const float4*)(attD + cg * 4);
    float4 av[4] = {a0, a1, a2, a3};
#pragma unroll
    for (int j = 0; j < 4; ++j) {
        int node = node0 + j;
        float4 a = av[j];
        float vs = dot4(a, sA);
        float vd = dot4(a, dA);
        vs += __shfl_xor(vs, 1, 64);
        vd += __shfl_xor(vd, 1, 64);
        if (node < n) {
            ushort4 q;
            q.x = f2bu(a.x); q.y = f2bu(a.y); q.z = f2bu(a.z); q.w = f2bu(a.w);
            *(ushort4*)(h1b + (long)node * H8 + cg * 4) = q;
            if ((lane & 1) == 0) {
                as1[node * 8 + (cg >> 1)] = vs;
                ad1[node * 8 + (cg >> 1)] = vd;
            }
        }
    }
}

// binA body: histogram for CSR block cb, transposed store
__device__ __forceinline__ void binA_body(int cb, const int* __restrict__ dst,
        int* __restrict__ bh, int e, int nb, int nblk, int* hist) {
    int t = threadIdx.x;
    hist[t] = 0;
    __syncthreads();
    int base = cb * CHUNK;
    int endj = min(base + CHUNK, e);
    for (int k0 = base + t * 4; k0 < endj; k0 += 1024) {
        if (k0 + 3 < endj) {
            int4 d4 = *(const int4*)(dst + k0);
            atomicAdd(&hist[d4.x >> BKS], 1);
            atomicAdd(&hist[d4.y >> BKS], 1);
            atomicAdd(&hist[d4.z >> BKS], 1);
            atomicAdd(&hist[d4.w >> BKS], 1);
        } else {
            for (int k = k0; k < endj; ++k) atomicAdd(&hist[dst[k] >> BKS], 1);
        }
    }
    __syncthreads();
    if (t < nb) bh[t * nblk + cb] = hist[t];
}

// scanB body: bucket j scans its per-block counts
__device__ __forceinline__ void scanB_body(int j, int* __restrict__ bh,
        int* __restrict__ btot, int nblk, int* ts) {
    int t = threadIdx.x;
    int v = (t < nblk) ? bh[j * nblk + t] : 0;
    ts[t] = v;
    __syncthreads();
    int run = v;
    for (int off = 1; off < 256; off <<= 1) {
        int y = (t >= off) ? ts[t - off] : 0;
        __syncthreads();
        run += y;
        ts[t] = run;
        __syncthreads();
    }
    if (t < nblk) bh[j * nblk + t] = run - v;
    if (t == 255) btot[j] = run;
}

// binC body: scatter packed entries for CSR block cb
__device__ __forceinline__ void binC_body(int cb, const int* __restrict__ src,
        const int* __restrict__ dst, const int* __restrict__ bh,
        const int* __restrict__ bstart, uint_t* __restrict__ binned,
        int e, int nb, int nblk, int* off) {
    int t = threadIdx.x;
    if (t < nb) off[t] = bh[t * nblk + cb] + bstart[t];
    __syncthreads();
    int base = cb * CHUNK;
    int endj = min(base + CHUNK, e);
    for (int k0 = base + t * 4; k0 < endj; k0 += 1024) {
        if (k0 + 3 < endj) {
            int4 d4 = *(const int4*)(dst + k0);
            int4 s4 = *(const int4*)(src + k0);
            int p0 = atomicAdd(&off[d4.x >> BKS], 1);
            binned[p0] = ((uint_t)(d4.x & BMASK) << 17) | (uint_t)s4.x;
            int p1 = atomicAdd(&off[d4.y >> BKS], 1);
            binned[p1] = ((uint_t)(d4.y & BMASK) << 17) | (uint_t)s4.y;
            int p2 = atomicAdd(&off[d4.z >> BKS], 1);
            binned[p2] = ((uint_t)(d4.z & BMASK) << 17) | (uint_t)s4.z;
            int p3 = atomicAdd(&off[d4.w >> BKS], 1);
            binned[p3] = ((uint_t)(d4.w & BMASK) << 17) | (uint_t)s4.w;
        } else {
            for (int k = k0; k < endj; ++k) {
                int d = dst[k], s = src[k];
                int p = atomicAdd(&off[d >> BKS], 1);
                binned[p] = ((uint_t)(d & BMASK) << 17) | (uint_t)s;
            }
        }
    }
}

// ---------------- fused launches: CSR stage ∥ gemm1 slice ----------------

__global__ __launch_bounds__(256) void k_fuseA(const int* __restrict__ dst,
        int* __restrict__ bh, int e, int nb, int nblk,
        const float* __restrict__ x, const float* __restrict__ W,
        const float* __restrict__ attS, const float* __restrict__ attD,
        ushort_t* __restrict__ h1b, float* __restrict__ as1,
        float* __restrict__ ad1, int n) {
    __shared__ float smem[FIN * H8];   // 32 KB arena
    if ((int)blockIdx.x < nblk)
        binA_body(blockIdx.x, dst, bh, e, nb, nblk, (int*)smem);
    else
        gemm1_body(blockIdx.x - nblk, x, W, attS, attD, h1b, as1, ad1, n, smem);
}

__global__ __launch_bounds__(256) void k_fuseB(int* __restrict__ bh,
        int* __restrict__ btot, int nblk, int nb, int g1ofs,
        const float* __restrict__ x, const float* __restrict__ W,
        const float* __restrict__ attS, const float* __restrict__ attD,
        ushort_t* __restrict__ h1b, float* __restrict__ as1,
        float* __restrict__ ad1, int n) {
    __shared__ float smem[FIN * H8];
    if ((int)blockIdx.x < nb)
        scanB_body(blockIdx.x, bh, btot, nblk, (int*)smem);
    else
        gemm1_body(g1ofs + blockIdx.x - nb, x, W, attS, attD, h1b, as1, ad1, n, smem);
}

__global__ __launch_bounds__(256) void k_fuseC(const int* __restrict__ src,
        const int* __restrict__ dst, const int* __restrict__ bh,
        const int* __restrict__ bstart, uint_t* __restrict__ binned,
        int e, int nb, int nblk, int g1ofs,
        const float* __restrict__ x, const float* __restrict__ W,
        const float* __restrict__ attS, const float* __restrict__ attD,
        ushort_t* __restrict__ h1b, float* __restrict__ as1,
        float* __restrict__ ad1, int n) {
    __shared__ float smem[FIN * H8];
    if ((int)blockIdx.x < nblk)
        binC_body(blockIdx.x, src, dst, bh, bstart, binned, e, nb, nblk, (int*)smem);
    else
        gemm1_body(g1ofs + blockIdx.x - nblk, x, W, attS, attD, h1b, as1, ad1, n, smem);
}

// Scan of bucket totals -> bstart[0..nb]
__global__ __launch_bounds__(256) void k_scanT(const int* __restrict__ btot,
        int* __restrict__ bstart, int nb) {
    __shared__ int ts[256];
    int j = threadIdx.x;
    int s = (j < nb) ? btot[j] : 0;
    ts[j] = s;
    __syncthreads();
    int run = s;
    for (int off = 1; off < 256; off <<= 1) {
        int y = (j >= off) ? ts[j - off] : 0;
        __syncthreads();
        run += y;
        ts[j] = run;
        __syncthreads();
    }
    if (j < nb) bstart[j] = run - s;
    if (j == nb - 1) bstart[nb] = run;
}

// Fused per-bucket CSR finalize: degree hist + scan + selfloop + scatter.
__global__ __launch_bounds__(256) void k_bucket(const uint_t* __restrict__ binned,
        const int* __restrict__ bstart, int* __restrict__ rp, int* __restrict__ col,
        int e, int n, int nb) {
    __shared__ int deg[512];
    __shared__ int ts[256];
    int b = blockIdx.x, t = threadIdx.x;
    int node0 = b << BKS;
    int S = bstart[b];
    int Se = bstart[b + 1];
    deg[t] = 0; deg[t + 256] = 0;
    __syncthreads();
    for (int k = S + t; k < Se; k += 256)
        atomicAdd(&deg[binned[k] >> 17], 1);
    __syncthreads();
    int g0 = node0 + 2 * t, g1 = g0 + 1;
    int c0 = (g0 < n) ? deg[2 * t] + 1 : 0;      // +1 = self-loop
    int c1 = (g1 < n) ? deg[2 * t + 1] + 1 : 0;
    int s = c0 + c1;
    ts[t] = s;
    __syncthreads();
    int run = s;
    for (int off = 1; off < 256; off <<= 1) {
        int y = (t >= off) ? ts[t - off] : 0;
        __syncthreads();
        run += y;
        ts[t] = run;
        __syncthreads();
    }
    int ex = run - s;
    int base = S + node0;
    int p0 = base + ex, p1 = base + ex + c0;
    if (g0 < n) { rp[g0] = p0; col[p0] = g0; deg[2 * t] = p0 + 1; }
    if (g1 < n) { rp[g1] = p1; col[p1] = g1; deg[2 * t + 1] = p1 + 1; }
    if (b == nb - 1 && t == 0) rp[n] = e + n;
    __syncthreads();
    for (int k = S + t; k < Se; k += 256) {
        uint_t pk = binned[k];
        int dLow = pk >> 17;
        int sv = (int)(pk & 0x1FFFFu);
        int p = atomicAdd(&deg[dLow], 1);
        col[p] = sv;
    }
}

// ---------------- Layer 1 aggregation + bias + ReLU (bf16 z out) ----------------
// TWO nodes per wave with independent interleaved round streams.

__global__ __launch_bounds__(256) void k_agg1(const int* __restrict__ rp,
        const int* __restrict__ col, const ushort_t* __restrict__ h1b,
        const float* __restrict__ as1, const float* __restrict__ ad1,
        const float* __restrict__ b1, ushort_t* __restrict__ z1b, int n) {
    int w = (blockIdx.x * 256 + threadIdx.x) >> 6;
    int lane = threadIdx.x & 63;
    int iA = w * 2, iB = iA + 1;
    if (iA >= n) return;
    bool hasB = (iB < n);
    int slot = lane >> 3;   // edge sub-index (0..7)
    int h2 = lane & 7;      // head; channels h2*8 .. h2*8+7
    int l16 = lane & 15;
    int begA = rp[iA], endA = rp[iA + 1];
    int begB = hasB ? rp[iB] : 0, endB = hasB ? rp[iB + 1] : 0;
    int lastA = endA - 1, lastB = endB - 1;
    float adiA = ad1[iA * 8 + h2];
    float adiB = hasB ? ad1[iB * 8 + h2] : 0.f;
    float denA = 0.f, denB = 0.f;
    float numA[8] = {0.f, 0.f, 0.f, 0.f, 0.f, 0.f, 0.f, 0.f};
    float numB[8] = {0.f, 0.f, 0.f, 0.f, 0.f, 0.f, 0.f, 0.f};
    int roundsA = (endA - begA + 15) >> 4;
    int roundsB = hasB ? ((endB - begB + 15) >> 4) : 0;
    int rmax = max(roundsA, roundsB);
    int vA = col[min(begA + l16, lastA)];
    int vB = roundsB ? col[min(begB + l16, lastB)] : 0;
    for (int r = 0; r < rmax; ++r) {
        bool mA = r < roundsA, mB = r < roundsB;   // wave-uniform
        int kA0 = begA + r * 16, kB0 = begB + r * 16;
        int vnA = 0, vnB = 0;
        if (r + 1 < roundsA) vnA = col[min(kA0 + 16 + l16, lastA)];
        if (r + 1 < roundsB) vnB = col[min(kB0 + 16 + l16, lastB)];
        float pAa = 0.f, pAb = 0.f, pBa = 0.f, pBb = 0.f;
        uint4 uaA, ubA, uaB, ubB;
        if (mA) {
            int s0 = __shfl(vA, slot, 64);
            int s1 = __shfl(vA, 8 + slot, 64);
            float sv0 = as1[s0 * 8 + h2];
            float sv1 = as1[s1 * 8 + h2];
            uaA = *((const uint4*)(h1b + ((size_t)(unsigned)s0 << 6)) + h2);
            ubA = *((const uint4*)(h1b + ((size_t)(unsigned)s1 << 6)) + h2);
            float e0 = sv0 + adiA;
            e0 = fmaxf(e0, 0.f) + 0.2f * fminf(e0, 0.f);
            pAa = (kA0 + slot < endA) ? __expf(e0) : 0.f;
            float e1 = sv1 + adiA;
            e1 = fmaxf(e1, 0.f) + 0.2f * fminf(e1, 0.f);
            pAb = (kA0 + 8 + slot < endA) ? __expf(e1) : 0.f;
            denA += pAa + pAb;
        }
        if (mB) {
            int s0 = __shfl(vB, slot, 64);
            int s1 = __shfl(vB, 8 + slot, 64);
            float sv0 = as1[s0 * 8 + h2];
            float sv1 = as1[s1 * 8 + h2];
            uaB = *((const uint4*)(h1b + ((size_t)(unsigned)s0 << 6)) + h2);
            ubB = *((const uint4*)(h1b + ((size_t)(unsigned)s1 << 6)) + h2);
            float e0 = sv0 + adiB;
            e0 = fmaxf(e0, 0.f) + 0.2f * fminf(e0, 0.f);
            pBa = (kB0 + slot < endB) ? __expf(e0) : 0.f;
            float e1 = sv1 + adiB;
            e1 = fmaxf(e1, 0.f) + 0.2f * fminf(e1, 0.f);
            pBb = (kB0 + 8 + slot < endB) ? __expf(e1) : 0.f;
            denB += pBa + pBb;
        }
#define ACC8(NUM, P, U)                                                    \
        {                                                                  \
            NUM[0] += (P) * __uint_as_float((U).x << 16);                  \
            NUM[1] += (P) * __uint_as_float((U).x & 0xffff0000u);          \
            NUM[2] += (P) * __uint_as_float((U).y << 16);                  \
            NUM[3] += (P) * __uint_as_float((U).y & 0xffff0000u);          \
            NUM[4] += (P) * __uint_as_float((U).z << 16);                  \
            NUM[5] += (P) * __uint_as_float((U).z & 0xffff0000u);          \
            NUM[6] += (P) * __uint_as_float((U).w << 16);                  \
            NUM[7] += (P) * __uint_as_float((U).w & 0xffff0000u);          \
        }
        if (mA) { ACC8(numA, pAa, uaA) ACC8(numA, pAb, ubA) }
        if (mB) { ACC8(numB, pBa, uaB) ACC8(numB, pBb, ubB) }
#undef ACC8
        vA = vnA; vB = vnB;
    }
#pragma unroll
    for (int q = 0; q < 8; ++q) {
        numA[q] += __shfl_xor(numA[q], 8, 64);
        numA[q] += __shfl_xor(numA[q], 16, 64);
        numA[q] += __shfl_xor(numA[q], 32, 64);
        numB[q] += __shfl_xor(numB[q], 8, 64);
        numB[q] += __shfl_xor(numB[q], 16, 64);
        numB[q] += __shfl_xor(numB[q], 32, 64);
    }
    denA += __shfl_xor(denA, 8, 64);
    denA += __shfl_xor(denA, 16, 64);
    denA += __shfl_xor(denA, 32, 64);
    denB += __shfl_xor(denB, 8, 64);
    denB += __shfl_xor(denB, 16, 64);
    denB += __shfl_xor(denB, 32, 64);
    if (lane < 16) {
        bool isB = lane >= 8;
        if (!isB || hasB) {
            int node = isB ? iB : iA;
            const float* nm = isB ? numB : numA;
            float invd = 1.0f / ((isB ? denB : denA) + 1e-16f);
            float4 b0 = *(const float4*)(b1 + h2 * 8);
            float4 b1v = *(const float4*)(b1 + h2 * 8 + 4);
            float o0 = fmaxf(nm[0] * invd + b0.x, 0.f);
            float o1 = fmaxf(nm[1] * invd + b0.y, 0.f);
            float o2 = fmaxf(nm[2] * invd + b0.z, 0.f);
            float o3 = fmaxf(nm[3] * invd + b0.w, 0.f);
            float o4 = fmaxf(nm[4] * invd + b1v.x, 0.f);
            float o5 = fmaxf(nm[5] * invd + b1v.y, 0.f);
            float o6 = fmaxf(nm[6] * invd + b1v.z, 0.f);
            float o7 = fmaxf(nm[7] * invd + b1v.w, 0.f);
            uint4 q;
            q.x = (uint_t)f2bu(o0) | ((uint_t)f2bu(o1) << 16);
            q.y = (uint_t)f2bu(o2) | ((uint_t)f2bu(o3) << 16);
            q.z = (uint_t)f2bu(o4) | ((uint_t)f2bu(o5) << 16);
            q.w = (uint_t)f2bu(o6) | ((uint_t)f2bu(o7) << 16);
            *(uint4*)(z1b + (size_t)node * H8 + h2 * 8) = q;
        }
    }
}

// ---------------- Layer 2 GEMM + attention dots (bf16 z in, bf16 h2 out) ------

__global__ __launch_bounds__(256) void k_gemm2(const ushort_t* __restrict__ z1b,
        const float* __restrict__ W2, const float* __restrict__ attS,
        const float* __restrict__ attD, ushort_t* __restrict__ h2b,
        float* __restrict__ as2, float* __restrict__ ad2) {
    __shared__ float ws[H8 * NC];     // 4 KB
    __shared__ float zs[16][H8 + 1];  // padded
    int t = threadIdx.x;
    for (int j = t; j < H8 * NC; j += 256) ws[j] = W2[j];
    int n0 = blockIdx.x * 16;
    {
        const ushort4* zp = (const ushort4*)(z1b + (size_t)n0 * H8);
        ushort4 q = zp[t];
        int r = t >> 4, k2 = (t & 15) * 4;
        zs[r][k2 + 0] = bu2f(q.x);
        zs[r][k2 + 1] = bu2f(q.y);
        zs[r][k2 + 2] = bu2f(q.z);
        zs[r][k2 + 3] = bu2f(q.w);
    }
    __syncthreads();
    int c = t & 15, g = t >> 4;
    float acc = 0.f;
#pragma unroll 8
    for (int k = 0; k < H8; ++k) acc += zs[g][k] * ws[k * NC + c];
    h2b[(long)(n0 + g) * NC + c] = f2bu(acc);
    float vs = acc * attS[c], vd = acc * attD[c];
    for (int off = 1; off < 16; off <<= 1) {
        vs += __shfl_xor(vs, off, 64);
        vd += __shfl_xor(vd, off, 64);
    }
    if (c == 0) { as2[n0 + g] = vs; ad2[n0 + g] = vd; }
}

// ---------------- Layer 2 aggregation + bias + log_softmax ----------------

__global__ __launch_bounds__(256) void k_agg2(const int* __restrict__ rp,
        const int* __restrict__ col, const ushort_t* __restrict__ h2b,
        const float* __restrict__ as2, const float* __restrict__ ad2,
        const float* __restrict__ b2, float* __restrict__ out, int n) {
    int i = (blockIdx.x * 256 + threadIdx.x) >> 6;
    int lane = threadIdx.x & 63;
    if (i >= n) return;
    int grp = lane >> 3;    // edge group (0..7)
    int cp = lane & 7;      // channel pair: ch 2cp, 2cp+1
    int beg = rp[i], end = rp[i + 1];
    int last = end - 1;
    int deg = end - beg;
    float adi = ad2[i];
    const uint_t* h2u = (const uint_t*)h2b;
    float denp = 0.f, nx = 0.f, ny = 0.f;
    int rounds = (deg + 31) >> 5;
    for (int r = 0; r < rounds; ++r) {
        int k = beg + r * 32;
        int rem = end - k;               // wave-uniform, > 0
        int v = col[min(k + (lane & 31), last)];
        float sv = as2[v];
        float e = sv + adi;
        e = fmaxf(e, 0.f) + 0.2f * fminf(e, 0.f);
        int lim = min(rem, 32);
        float p = (lane < lim) ? __expf(e) : 0.f;
        denp += p;
#define AGG2_PAIR(S0, S1)                                                  \
        {                                                                  \
            int i0 = (S0) * 8 + grp, i1 = (S1) * 8 + grp;                  \
            int r0 = __shfl(v, i0, 64), r1 = __shfl(v, i1, 64);            \
            float q0 = __shfl(p, i0, 64), q1 = __shfl(p, i1, 64);          \
            uint_t u0 = h2u[((size_t)(unsigned)r0 << 3) + cp];             \
            uint_t u1 = h2u[((size_t)(unsigned)r1 << 3) + cp];             \
            nx += q0 * __uint_as_float(u0 << 16);                          \
            ny += q0 * __uint_as_float(u0 & 0xffff0000u);                  \
            nx += q1 * __uint_as_float(u1 << 16);                          \
            ny += q1 * __uint_as_float(u1 & 0xffff0000u);                  \
        }
        AGG2_PAIR(0, 1)
        if (lim > 16) AGG2_PAIR(2, 3)
#undef AGG2_PAIR
    }
    nx += __shfl_xor(nx, 8, 64);  ny += __shfl_xor(ny, 8, 64);
    nx += __shfl_xor(nx, 16, 64); ny += __shfl_xor(ny, 16, 64);
    nx += __shfl_xor(nx, 32, 64); ny += __shfl_xor(ny, 32, 64);
    denp += __shfl_xor(denp, 1, 64);
    denp += __shfl_xor(denp, 2, 64);
    denp += __shfl_xor(denp, 4, 64);
    denp += __shfl_xor(denp, 8, 64);
    denp += __shfl_xor(denp, 16, 64);
    denp += __shfl_xor(denp, 32, 64);
    float invd = 1.0f / (denp + 1e-16f);
    float2 bp = ((const float2*)b2)[cp];
    float ox = nx * invd + bp.x;
    float oy = ny * invd + bp.y;
    float mx = fmaxf(ox, oy);
    mx = fmaxf(mx, __shfl_xor(mx, 1, 64));
    mx = fmaxf(mx, __shfl_xor(mx, 2, 64));
    mx = fmaxf(mx, __shfl_xor(mx, 4, 64));
    float sm = __expf(ox - mx) + __expf(oy - mx);
    sm += __shfl_xor(sm, 1, 64);
    sm += __shfl_xor(sm, 2, 64);
    sm += __shfl_xor(sm, 4, 64);
    float lg = mx + __logf(sm);
    if (lane < 8) {
        float2 res = {ox - lg, oy - lg};
        ((float2*)(out + (size_t)i * NC))[cp] = res;
    }
}

// ---------------- launcher ----------------

extern "C" void kernel_launch(void* const* d_in, const int* in_sizes, int n_in,
                              void* d_out, int out_size, void* d_ws, size_t ws_size,
                              hipStream_t stream) {
    const float* x     = (const float*)d_in[0];
    const int*   ei    = (const int*)d_in[1];
    const float* W1    = (const float*)d_in[2];
    const float* attS1 = (const float*)d_in[3];
    const float* attD1 = (const float*)d_in[4];
    const float* b1    = (const float*)d_in[5];
    const float* W2    = (const float*)d_in[6];
    const float* attS2 = (const float*)d_in[7];
    const float* attD2 = (const float*)d_in[8];
    const float* b2    = (const float*)d_in[9];
    float* out = (float*)d_out;

    const int N = NN;
    const int E = in_sizes[1] / 2;
    const int NB = (N + (1 << BKS) - 1) >> BKS;      // buckets (196)
    const int NBLK = (E + CHUNK - 1) / CHUNK;        // binning blocks (196)

    ushort_t* z1b = (ushort_t*)d_ws;            // N*64 bf16 (aliased by binned)
    float* as1 = (float*)(z1b + (size_t)N * H8);// N*8
    float* ad1 = as1 + (size_t)N * 8;           // N*8
    float* as2 = ad1 + (size_t)N * 8;           // N
    float* ad2 = as2 + N;                       // N
    ushort_t* h1b = (ushort_t*)(ad2 + N);       // N*64 bf16
    ushort_t* h2b = h1b + (size_t)N * H8;       // N*16 bf16
    int* rp   = (int*)(h2b + (size_t)N * NC);   // N+1
    int* col  = rp + (N + 1);                   // E+N
    int* bh   = col + (E + N);                  // NB*NBLK (bucket-major)
    int* btot = bh + (size_t)NB * NBLK;         // NB
    int* bstart = btot + NB;                    // NB+1
    uint_t* binned = (uint_t*)z1b;              // E * 4B

    const int* srcp = ei;
    const int* dstp = ei + E;

    const int G1 = (N + 63) / 64;               // total gemm1 blocks (1563)
    const int G1A = G1 * 1 / 3;
    const int G1B = G1 * 1 / 3;
    const int G1C = G1 - G1A - G1B;

    k_fuseA<<<NBLK + G1A, 256, 0, stream>>>(dstp, bh, E, NB, NBLK,
            x, W1, attS1, attD1, h1b, as1, ad1, N);
    k_fuseB<<<NB + G1B, 256, 0, stream>>>(bh, btot, NBLK, NB, G1A,
            x, W1, attS1, attD1, h1b, as1, ad1, N);
    k_scanT<<<1, 256, 0, stream>>>(btot, bstart, NB);
    k_fuseC<<<NBLK + G1C, 256, 0, stream>>>(srcp, dstp, bh, bstart, binned,
            E, NB, NBLK, G1A + G1B, x, W1, attS1, attD1, h1b, as1, ad1, N);
    k_bucket<<<NB, 256, 0, stream>>>(binned, bstart, rp, col, E, N, NB);

    k_agg1<<<(N + 7) / 8, 256, 0, stream>>>(rp, col, h1b, as1, ad1, b1, z1b, N);
    k_gemm2<<<N / 16, 256, 0, stream>>>(z1b, W2, attS2, attD2, h2b, as2, ad2);
    k_agg2<<<(N + 3) / 4, 256, 0, stream>>>(rp, col, h2b, as2, ad2, b2, out, N);
}

// Round 20
// 168.386 us; speedup vs baseline: 1.1021x; 1.0693x over previous
//
#include <hip/hip_runtime.h>
#include <hip/hip_bf16.h>

#define NN 100000
#define FIN 128
#define H8 64      // heads*hid = 8*8
#define NC 16
#define BKS 9      // bucket shift: 512 nodes/bucket
#define BMASK 511
#define CHUNK 8192 // edges per binning block

typedef unsigned short ushort_t;
typedef unsigned int uint_t;

__device__ __forceinline__ float bu2f(ushort_t u) {
    unsigned v = ((unsigned)u) << 16;
    return __uint_as_float(v);
}
__device__ __forceinline__ ushort_t f2bu(float f) {
    __hip_bfloat16 h = __float2bfloat16(f);
    return *reinterpret_cast<ushort_t*>(&h);
}
__device__ __forceinline__ float dot4(float4 a, float4 b) {
    return a.x * b.x + a.y * b.y + a.z * b.z + a.w * b.w;
}
__device__ __forceinline__ void fma4(float4& a, float s, float4 w) {
    a.x += s * w.x; a.y += s * w.y; a.z += s * w.z; a.w += s * w.w;
}

// ---------------- device bodies (for fused launches) ----------------

// gemm1 body: block gb handles nodes [gb*64, gb*64+64); ws = 32KB LDS arena
__device__ __forceinline__ void gemm1_body(int gb,
        const float* __restrict__ x, const float* __restrict__ W,
        const float* __restrict__ attS, const float* __restrict__ attD,
        ushort_t* __restrict__ h1b, float* __restrict__ as1,
        float* __restrict__ ad1, int n, float* ws) {
    int t = threadIdx.x;
    const float4* W4 = (const float4*)W;
    float4* ws4 = (float4*)ws;
    for (int j = t; j < FIN * H8 / 4; j += 256) ws4[j] = W4[j];
    __syncthreads();

    int wv = t >> 6, lane = t & 63;
    int ng = lane >> 4, cg = lane & 15;
    int node0 = (gb * 4 + wv) * 16 + ng * 4;

    int r0 = min(node0 + 0, n - 1), r1 = min(node0 + 1, n - 1);
    int r2 = min(node0 + 2, n - 1), r3 = min(node0 + 3, n - 1);
    const float* xp0 = x + (long)r0 * FIN;
    const float* xp1 = x + (long)r1 * FIN;
    const float* xp2 = x + (long)r2 * FIN;
    const float* xp3 = x + (long)r3 * FIN;

    float4 a0 = {0, 0, 0, 0}, a1 = {0, 0, 0, 0}, a2 = {0, 0, 0, 0}, a3 = {0, 0, 0, 0};
#pragma unroll 2
    for (int k = 0; k < FIN; k += 4) {
        float4 xa = *(const float4*)(xp0 + k);
        float4 xb = *(const float4*)(xp1 + k);
        float4 xc = *(const float4*)(xp2 + k);
        float4 xd = *(const float4*)(xp3 + k);
        float4 w0 = *(const float4*)(ws + (k + 0) * H8 + cg * 4);
        float4 w1 = *(const float4*)(ws + (k + 1) * H8 + cg * 4);
        float4 w2 = *(const float4*)(ws + (k + 2) * H8 + cg * 4);
        float4 w3 = *(const float4*)(ws + (k + 3) * H8 + cg * 4);
        fma4(a0, xa.x, w0); fma4(a0, xa.y, w1); fma4(a0, xa.z, w2); fma4(a0, xa.w, w3);
        fma4(a1, xb.x, w0); fma4(a1, xb.y, w1); fma4(a1, xb.z, w2); fma4(a1, xb.w, w3);
        fma4(a2, xc.x, w0); fma4(a2, xc.y, w1); fma4(a2, xc.z, w2); fma4(a2, xc.w, w3);
        fma4(a3, xd.x, w0); fma4(a3, xd.y, w1); fma4(a3, xd.z, w2); fma4(a3, xd.w, w3);
    }

    float4 sA = *(const float4*)(attS + cg * 4);
    float4 dA = *(const float4*)(attD + cg * 4);
    float4 av[4] = {a0, a1, a2, a3};
#pragma unroll
    for (int j = 0; j < 4; ++j) {
        int node = node0 + j;
        float4 a = av[j];
        float vs = dot4(a, sA);
        float vd = dot4(a, dA);
        vs += __shfl_xor(vs, 1, 64);
        vd += __shfl_xor(vd, 1, 64);
        if (node < n) {
            ushort4 q;
            q.x = f2bu(a.x); q.y = f2bu(a.y); q.z = f2bu(a.z); q.w = f2bu(a.w);
            *(ushort4*)(h1b + (long)node * H8 + cg * 4) = q;
            if ((lane & 1) == 0) {
                as1[node * 8 + (cg >> 1)] = vs;
                ad1[node * 8 + (cg >> 1)] = vd;
            }
        }
    }
}

// binA body: histogram for CSR block cb, transposed store
__device__ __forceinline__ void binA_body(int cb, const int* __restrict__ dst,
        int* __restrict__ bh, int e, int nb, int nblk, int* hist) {
    int t = threadIdx.x;
    hist[t] = 0;
    __syncthreads();
    int base = cb * CHUNK;
    int endj = min(base + CHUNK, e);
    for (int k0 = base + t * 4; k0 < endj; k0 += 1024) {
        if (k0 + 3 < endj) {
            int4 d4 = *(const int4*)(dst + k0);
            atomicAdd(&hist[d4.x >> BKS], 1);
            atomicAdd(&hist[d4.y >> BKS], 1);
            atomicAdd(&hist[d4.z >> BKS], 1);
            atomicAdd(&hist[d4.w >> BKS], 1);
        } else {
            for (int k = k0; k < endj; ++k) atomicAdd(&hist[dst[k] >> BKS], 1);
        }
    }
    __syncthreads();
    if (t < nb) bh[t * nblk + cb] = hist[t];
}

// scanB body: bucket j scans its per-block counts
__device__ __forceinline__ void scanB_body(int j, int* __restrict__ bh,
        int* __restrict__ btot, int nblk, int* ts) {
    int t = threadIdx.x;
    int v = (t < nblk) ? bh[j * nblk + t] : 0;
    ts[t] = v;
    __syncthreads();
    int run = v;
    for (int off = 1; off < 256; off <<= 1) {
        int y = (t >= off) ? ts[t - off] : 0;
        __syncthreads();
        run += y;
        ts[t] = run;
        __syncthreads();
    }
    if (t < nblk) bh[j * nblk + t] = run - v;
    if (t == 255) btot[j] = run;
}

// binC body: scatter packed entries for CSR block cb
__device__ __forceinline__ void binC_body(int cb, const int* __restrict__ src,
        const int* __restrict__ dst, const int* __restrict__ bh,
        const int* __restrict__ bstart, uint_t* __restrict__ binned,
        int e, int nb, int nblk, int* off) {
    int t = threadIdx.x;
    if (t < nb) off[t] = bh[t * nblk + cb] + bstart[t];
    __syncthreads();
    int base = cb * CHUNK;
    int endj = min(base + CHUNK, e);
    for (int k0 = base + t * 4; k0 < endj; k0 += 1024) {
        if (k0 + 3 < endj) {
            int4 d4 = *(const int4*)(dst + k0);
            int4 s4 = *(const int4*)(src + k0);
            int p0 = atomicAdd(&off[d4.x >> BKS], 1);
            binned[p0] = ((uint_t)(d4.x & BMASK) << 17) | (uint_t)s4.x;
            int p1 = atomicAdd(&off[d4.y >> BKS], 1);
            binned[p1] = ((uint_t)(d4.y & BMASK) << 17) | (uint_t)s4.y;
            int p2 = atomicAdd(&off[d4.z >> BKS], 1);
            binned[p2] = ((uint_t)(d4.z & BMASK) << 17) | (uint_t)s4.z;
            int p3 = atomicAdd(&off[d4.w >> BKS], 1);
            binned[p3] = ((uint_t)(d4.w & BMASK) << 17) | (uint_t)s4.w;
        } else {
            for (int k = k0; k < endj; ++k) {
                int d = dst[k], s = src[k];
                int p = atomicAdd(&off[d >> BKS], 1);
                binned[p] = ((uint_t)(d & BMASK) << 17) | (uint_t)s;
            }
        }
    }
}

// ---------------- fused launches: CSR stage ∥ gemm1 slice ----------------

__global__ __launch_bounds__(256) void k_fuseA(const int* __restrict__ dst,
        int* __restrict__ bh, int e, int nb, int nblk,
        const float* __restrict__ x, const float* __restrict__ W,
        const float* __restrict__ attS, const float* __restrict__ attD,
        ushort_t* __restrict__ h1b, float* __restrict__ as1,
        float* __restrict__ ad1, int n) {
    __shared__ float smem[FIN * H8];   // 32 KB arena
    if ((int)blockIdx.x < nblk)
        binA_body(blockIdx.x, dst, bh, e, nb, nblk, (int*)smem);
    else
        gemm1_body(blockIdx.x - nblk, x, W, attS, attD, h1b, as1, ad1, n, smem);
}

__global__ __launch_bounds__(256) void k_fuseB(int* __restrict__ bh,
        int* __restrict__ btot, int nblk, int nb, int g1ofs,
        const float* __restrict__ x, const float* __restrict__ W,
        const float* __restrict__ attS, const float* __restrict__ attD,
        ushort_t* __restrict__ h1b, float* __restrict__ as1,
        float* __restrict__ ad1, int n) {
    __shared__ float smem[FIN * H8];
    if ((int)blockIdx.x < nb)
        scanB_body(blockIdx.x, bh, btot, nblk, (int*)smem);
    else
        gemm1_body(g1ofs + blockIdx.x - nb, x, W, attS, attD, h1b, as1, ad1, n, smem);
}

__global__ __launch_bounds__(256) void k_fuseC(const int* __restrict__ src,
        const int* __restrict__ dst, const int* __restrict__ bh,
        const int* __restrict__ bstart, uint_t* __restrict__ binned,
        int e, int nb, int nblk, int g1ofs,
        const float* __restrict__ x, const float* __restrict__ W,
        const float* __restrict__ attS, const float* __restrict__ attD,
        ushort_t* __restrict__ h1b, float* __restrict__ as1,
        float* __restrict__ ad1, int n) {
    __shared__ float smem[FIN * H8];
    if ((int)blockIdx.x < nblk)
        binC_body(blockIdx.x, src, dst, bh, bstart, binned, e, nb, nblk, (int*)smem);
    else
        gemm1_body(g1ofs + blockIdx.x - nblk, x, W, attS, attD, h1b, as1, ad1, n, smem);
}

// Scan of bucket totals -> bstart[0..nb]
__global__ __launch_bounds__(256) void k_scanT(const int* __restrict__ btot,
        int* __restrict__ bstart, int nb) {
    __shared__ int ts[256];
    int j = threadIdx.x;
    int s = (j < nb) ? btot[j] : 0;
    ts[j] = s;
    __syncthreads();
    int run = s;
    for (int off = 1; off < 256; off <<= 1) {
        int y = (j >= off) ? ts[j - off] : 0;
        __syncthreads();
        run += y;
        ts[j] = run;
        __syncthreads();
    }
    if (j < nb) bstart[j] = run - s;
    if (j == nb - 1) bstart[nb] = run;
}

// Fused per-bucket CSR finalize: degree hist + scan + selfloop + scatter.
__global__ __launch_bounds__(256) void k_bucket(const uint_t* __restrict__ binned,
        const int* __restrict__ bstart, int* __restrict__ rp, int* __restrict__ col,
        int e, int n, int nb) {
    __shared__ int deg[512];
    __shared__ int ts[256];
    int b = blockIdx.x, t = threadIdx.x;
    int node0 = b << BKS;
    int S = bstart[b];
    int Se = bstart[b + 1];
    deg[t] = 0; deg[t + 256] = 0;
    __syncthreads();
    for (int k = S + t; k < Se; k += 256)
        atomicAdd(&deg[binned[k] >> 17], 1);
    __syncthreads();
    int g0 = node0 + 2 * t, g1 = g0 + 1;
    int c0 = (g0 < n) ? deg[2 * t] + 1 : 0;      // +1 = self-loop
    int c1 = (g1 < n) ? deg[2 * t + 1] + 1 : 0;
    int s = c0 + c1;
    ts[t] = s;
    __syncthreads();
    int run = s;
    for (int off = 1; off < 256; off <<= 1) {
        int y = (t >= off) ? ts[t - off] : 0;
        __syncthreads();
        run += y;
        ts[t] = run;
        __syncthreads();
    }
    int ex = run - s;
    int base = S + node0;
    int p0 = base + ex, p1 = base + ex + c0;
    if (g0 < n) { rp[g0] = p0; col[p0] = g0; deg[2 * t] = p0 + 1; }
    if (g1 < n) { rp[g1] = p1; col[p1] = g1; deg[2 * t + 1] = p1 + 1; }
    if (b == nb - 1 && t == 0) rp[n] = e + n;
    __syncthreads();
    for (int k = S + t; k < Se; k += 256) {
        uint_t pk = binned[k];
        int dLow = pk >> 17;
        int sv = (int)(pk & 0x1FFFFu);
        int p = atomicAdd(&deg[dLow], 1);
        col[p] = sv;
    }
}

// ---------------- Layer 1 aggregation + bias + ReLU (bf16 z out) ----------------
// TWO nodes per wave with independent interleaved round streams.

__global__ __launch_bounds__(256) void k_agg1(const int* __restrict__ rp,
        const int* __restrict__ col, const ushort_t* __restrict__ h1b,
        const float* __restrict__ as1, const float* __restrict__ ad1,
        const float* __restrict__ b1, ushort_t* __restrict__ z1b, int n) {
    int w = (blockIdx.x * 256 + threadIdx.x) >> 6;
    int lane = threadIdx.x & 63;
    int iA = w * 2, iB = iA + 1;
    if (iA >= n) return;
    bool hasB = (iB < n);
    int slot = lane >> 3;   // edge sub-index (0..7)
    int h2 = lane & 7;      // head; channels h2*8 .. h2*8+7
    int l16 = lane & 15;
    int begA = rp[iA], endA = rp[iA + 1];
    int begB = hasB ? rp[iB] : 0, endB = hasB ? rp[iB + 1] : 0;
    int lastA = endA - 1, lastB = endB - 1;
    float adiA = ad1[iA * 8 + h2];
    float adiB = hasB ? ad1[iB * 8 + h2] : 0.f;
    float denA = 0.f, denB = 0.f;
    float numA[8] = {0.f, 0.f, 0.f, 0.f, 0.f, 0.f, 0.f, 0.f};
    float numB[8] = {0.f, 0.f, 0.f, 0.f, 0.f, 0.f, 0.f, 0.f};
    int roundsA = (endA - begA + 15) >> 4;
    int roundsB = hasB ? ((endB - begB + 15) >> 4) : 0;
    int rmax = max(roundsA, roundsB);
    int vA = col[min(begA + l16, lastA)];
    int vB = roundsB ? col[min(begB + l16, lastB)] : 0;
    for (int r = 0; r < rmax; ++r) {
        bool mA = r < roundsA, mB = r < roundsB;   // wave-uniform
        int kA0 = begA + r * 16, kB0 = begB + r * 16;
        int vnA = 0, vnB = 0;
        if (r + 1 < roundsA) vnA = col[min(kA0 + 16 + l16, lastA)];
        if (r + 1 < roundsB) vnB = col[min(kB0 + 16 + l16, lastB)];
        float pAa = 0.f, pAb = 0.f, pBa = 0.f, pBb = 0.f;
        uint4 uaA, ubA, uaB, ubB;
        if (mA) {
            int s0 = __shfl(vA, slot, 64);
            int s1 = __shfl(vA, 8 + slot, 64);
            float sv0 = as1[s0 * 8 + h2];
            float sv1 = as1[s1 * 8 + h2];
            uaA = *((const uint4*)(h1b + ((size_t)(unsigned)s0 << 6)) + h2);
            ubA = *((const uint4*)(h1b + ((size_t)(unsigned)s1 << 6)) + h2);
            float e0 = sv0 + adiA;
            e0 = fmaxf(e0, 0.f) + 0.2f * fminf(e0, 0.f);
            pAa = (kA0 + slot < endA) ? __expf(e0) : 0.f;
            float e1 = sv1 + adiA;
            e1 = fmaxf(e1, 0.f) + 0.2f * fminf(e1, 0.f);
            pAb = (kA0 + 8 + slot < endA) ? __expf(e1) : 0.f;
            denA += pAa + pAb;
        }
        if (mB) {
            int s0 = __shfl(vB, slot, 64);
            int s1 = __shfl(vB, 8 + slot, 64);
            float sv0 = as1[s0 * 8 + h2];
            float sv1 = as1[s1 * 8 + h2];
            uaB = *((const uint4*)(h1b + ((size_t)(unsigned)s0 << 6)) + h2);
            ubB = *((const uint4*)(h1b + ((size_t)(unsigned)s1 << 6)) + h2);
            float e0 = sv0 + adiB;
            e0 = fmaxf(e0, 0.f) + 0.2f * fminf(e0, 0.f);
            pBa = (kB0 + slot < endB) ? __expf(e0) : 0.f;
            float e1 = sv1 + adiB;
            e1 = fmaxf(e1, 0.f) + 0.2f * fminf(e1, 0.f);
            pBb = (kB0 + 8 + slot < endB) ? __expf(e1) : 0.f;
            denB += pBa + pBb;
        }
#define ACC8(NUM, P, U)                                                    \
        {                                                                  \
            NUM[0] += (P) * __uint_as_float((U).x << 16);                  \
            NUM[1] += (P) * __uint_as_float((U).x & 0xffff0000u);          \
            NUM[2] += (P) * __uint_as_float((U).y << 16);                  \
            NUM[3] += (P) * __uint_as_float((U).y & 0xffff0000u);          \
            NUM[4] += (P) * __uint_as_float((U).z << 16);                  \
            NUM[5] += (P) * __uint_as_float((U).z & 0xffff0000u);          \
            NUM[6] += (P) * __uint_as_float((U).w << 16);                  \
            NUM[7] += (P) * __uint_as_float((U).w & 0xffff0000u);          \
        }
        if (mA) { ACC8(numA, pAa, uaA) ACC8(numA, pAb, ubA) }
        if (mB) { ACC8(numB, pBa, uaB) ACC8(numB, pBb, ubB) }
#undef ACC8
        vA = vnA; vB = vnB;
    }
#pragma unroll
    for (int q = 0; q < 8; ++q) {
        numA[q] += __shfl_xor(numA[q], 8, 64);
        numA[q] += __shfl_xor(numA[q], 16, 64);
        numA[q] += __shfl_xor(numA[q], 32, 64);
        numB[q] += __shfl_xor(numB[q], 8, 64);
        numB[q] += __shfl_xor(numB[q], 16, 64);
        numB[q] += __shfl_xor(numB[q], 32, 64);
    }
    denA += __shfl_xor(denA, 8, 64);
    denA += __shfl_xor(denA, 16, 64);
    denA += __shfl_xor(denA, 32, 64);
    denB += __shfl_xor(denB, 8, 64);
    denB += __shfl_xor(denB, 16, 64);
    denB += __shfl_xor(denB, 32, 64);
    if (lane < 16) {
        bool isB = lane >= 8;
        if (!isB || hasB) {
            int node = isB ? iB : iA;
            const float* nm = isB ? numB : numA;
            float invd = 1.0f / ((isB ? denB : denA) + 1e-16f);
            float4 b0 = *(const float4*)(b1 + h2 * 8);
            float4 b1v = *(const float4*)(b1 + h2 * 8 + 4);
            float o0 = fmaxf(nm[0] * invd + b0.x, 0.f);
            float o1 = fmaxf(nm[1] * invd + b0.y, 0.f);
            float o2 = fmaxf(nm[2] * invd + b0.z, 0.f);
            float o3 = fmaxf(nm[3] * invd + b0.w, 0.f);
            float o4 = fmaxf(nm[4] * invd + b1v.x, 0.f);
            float o5 = fmaxf(nm[5] * invd + b1v.y, 0.f);
            float o6 = fmaxf(nm[6] * invd + b1v.z, 0.f);
            float o7 = fmaxf(nm[7] * invd + b1v.w, 0.f);
            uint4 q;
            q.x = (uint_t)f2bu(o0) | ((uint_t)f2bu(o1) << 16);
            q.y = (uint_t)f2bu(o2) | ((uint_t)f2bu(o3) << 16);
            q.z = (uint_t)f2bu(o4) | ((uint_t)f2bu(o5) << 16);
            q.w = (uint_t)f2bu(o6) | ((uint_t)f2bu(o7) << 16);
            *(uint4*)(z1b + (size_t)node * H8 + h2 * 8) = q;
        }
    }
}

// ---------------- Layer 2 GEMM + attention dots (bf16 z in, bf16 h2 out) ------

__global__ __launch_bounds__(256) void k_gemm2(const ushort_t* __restrict__ z1b,
        const float* __restrict__ W2, const float* __restrict__ attS,
        const float* __restrict__ attD, ushort_t* __restrict__ h2b,
        float* __restrict__ as2, float* __restrict__ ad2) {
    __shared__ float ws[H8 * NC];     // 4 KB
    __shared__ float zs[16][H8 + 1];  // padded
    int t = threadIdx.x;
    for (int j = t; j < H8 * NC; j += 256) ws[j] = W2[j];
    int n0 = blockIdx.x * 16;
    {
        const ushort4* zp = (const ushort4*)(z1b + (size_t)n0 * H8);
        ushort4 q = zp[t];
        int r = t >> 4, k2 = (t & 15) * 4;
        zs[r][k2 + 0] = bu2f(q.x);
        zs[r][k2 + 1] = bu2f(q.y);
        zs[r][k2 + 2] = bu2f(q.z);
        zs[r][k2 + 3] = bu2f(q.w);
    }
    __syncthreads();
    int c = t & 15, g = t >> 4;
    float acc = 0.f;
#pragma unroll 8
    for (int k = 0; k < H8; ++k) acc += zs[g][k] * ws[k * NC + c];
    h2b[(long)(n0 + g) * NC + c] = f2bu(acc);
    float vs = acc * attS[c], vd = acc * attD[c];
    for (int off = 1; off < 16; off <<= 1) {
        vs += __shfl_xor(vs, off, 64);
        vd += __shfl_xor(vd, off, 64);
    }
    if (c == 0) { as2[n0 + g] = vs; ad2[n0 + g] = vd; }
}

// ---------------- Layer 2 aggregation + bias + log_softmax ----------------
// HALF-WAVE per node: hw = lane>>5 selects node, l32 = lane&31. Per 32-edge
// round each half computes p in its 32 lanes (no idle exp lanes), gathers in
// 8 stages of (4 edge-groups x 8 channel-pairs), reduces within the half
// (xor masks < 32), and does its own pairwise log-softmax + float2 store.

__global__ __launch_bounds__(256) void k_agg2(const int* __restrict__ rp,
        const int* __restrict__ col, const ushort_t* __restrict__ h2b,
        const float* __restrict__ as2, const float* __restrict__ ad2,
        const float* __restrict__ b2, float* __restrict__ out, int n) {
    int w = (blockIdx.x * 256 + threadIdx.x) >> 6;
    int lane = threadIdx.x & 63;
    int hw = lane >> 5, l32 = lane & 31;
    int i = w * 2 + hw;
    if (w * 2 >= n) return;          // n even -> both halves valid together
    int grp = l32 >> 3;              // edge group (0..3)
    int cp = l32 & 7;                // channel pair: ch 2cp, 2cp+1
    int beg = rp[i], end = rp[i + 1];
    int last = end - 1;
    float adi = ad2[i];
    const uint_t* h2u = (const uint_t*)h2b;
    float denp = 0.f, nx = 0.f, ny = 0.f;
    int rounds = (end - beg + 31) >> 5;
    int rmax = max(rounds, __shfl_xor(rounds, 32, 64));   // wave-uniform
    for (int r = 0; r < rmax; ++r) {
        int k = beg + r * 32;
        int rem = end - k;           // half-uniform (may be <= 0 on idle rounds)
        int v = col[min(max(k + l32, beg), last)];
        float sv = as2[v];
        float e = sv + adi;
        e = fmaxf(e, 0.f) + 0.2f * fminf(e, 0.f);
        float p = (l32 < rem) ? __expf(e) : 0.f;
        denp += p;
#define AGG2_ST2(S0, S1)                                                   \
        {                                                                  \
            int i0 = (S0) * 4 + grp, i1 = (S1) * 4 + grp;                  \
            int r0 = __shfl(v, hw * 32 + i0, 64);                          \
            int r1 = __shfl(v, hw * 32 + i1, 64);                          \
            float q0 = __shfl(p, hw * 32 + i0, 64);                        \
            float q1 = __shfl(p, hw * 32 + i1, 64);                        \
            uint_t u0 = h2u[((size_t)(unsigned)r0 << 3) + cp];             \
            uint_t u1 = h2u[((size_t)(unsigned)r1 << 3) + cp];             \
            nx += q0 * __uint_as_float(u0 << 16);                          \
            ny += q0 * __uint_as_float(u0 & 0xffff0000u);                  \
            nx += q1 * __uint_as_float(u1 << 16);                          \
            ny += q1 * __uint_as_float(u1 & 0xffff0000u);                  \
        }
        AGG2_ST2(0, 1)
        AGG2_ST2(2, 3)
        if (rem > 16) { AGG2_ST2(4, 5) AGG2_ST2(6, 7) }
#undef AGG2_ST2
    }
    // num over grp bits (3,4); den over all 5 half-local bits
    nx += __shfl_xor(nx, 8, 64);  ny += __shfl_xor(ny, 8, 64);
    nx += __shfl_xor(nx, 16, 64); ny += __shfl_xor(ny, 16, 64);
    denp += __shfl_xor(denp, 1, 64);
    denp += __shfl_xor(denp, 2, 64);
    denp += __shfl_xor(denp, 4, 64);
    denp += __shfl_xor(denp, 8, 64);
    denp += __shfl_xor(denp, 16, 64);
    float invd = 1.0f / (denp + 1e-16f);
    float2 bp = ((const float2*)b2)[cp];
    float ox = nx * invd + bp.x;
    float oy = ny * invd + bp.y;
    // log_softmax over 16 channels (8 pairs across cp bits 0..2)
    float mx = fmaxf(ox, oy);
    mx = fmaxf(mx, __shfl_xor(mx, 1, 64));
    mx = fmaxf(mx, __shfl_xor(mx, 2, 64));
    mx = fmaxf(mx, __shfl_xor(mx, 4, 64));
    float sm = __expf(ox - mx) + __expf(oy - mx);
    sm += __shfl_xor(sm, 1, 64);
    sm += __shfl_xor(sm, 2, 64);
    sm += __shfl_xor(sm, 4, 64);
    float lg = mx + __logf(sm);
    if (grp == 0 && i < n) {
        float2 res = {ox - lg, oy - lg};
        ((float2*)(out + (size_t)i * NC))[cp] = res;
    }
}

// ---------------- launcher ----------------

extern "C" void kernel_launch(void* const* d_in, const int* in_sizes, int n_in,
                              void* d_out, int out_size, void* d_ws, size_t ws_size,
                              hipStream_t stream) {
    const float* x     = (const float*)d_in[0];
    const int*   ei    = (const int*)d_in[1];
    const float* W1    = (const float*)d_in[2];
    const float* attS1 = (const float*)d_in[3];
    const float* attD1 = (const float*)d_in[4];
    const float* b1    = (const float*)d_in[5];
    const float* W2    = (const float*)d_in[6];
    const float* attS2 = (const float*)d_in[7];
    const float* attD2 = (const float*)d_in[8];
    const float* b2    = (const float*)d_in[9];
    float* out = (float*)d_out;

    const int N = NN;
    const int E = in_sizes[1] / 2;
    const int NB = (N + (1 << BKS) - 1) >> BKS;      // buckets (196)
    const int NBLK = (E + CHUNK - 1) / CHUNK;        // binning blocks (196)

    ushort_t* z1b = (ushort_t*)d_ws;            // N*64 bf16 (aliased by binned)
    float* as1 = (float*)(z1b + (size_t)N * H8);// N*8
    float* ad1 = as1 + (size_t)N * 8;           // N*8
    float* as2 = ad1 + (size_t)N * 8;           // N
    float* ad2 = as2 + N;                       // N
    ushort_t* h1b = (ushort_t*)(ad2 + N);       // N*64 bf16
    ushort_t* h2b = h1b + (size_t)N * H8;       // N*16 bf16
    int* rp   = (int*)(h2b + (size_t)N * NC);   // N+1
    int* col  = rp + (N + 1);                   // E+N
    int* bh   = col + (E + N);                  // NB*NBLK (bucket-major)
    int* btot = bh + (size_t)NB * NBLK;         // NB
    int* bstart = btot + NB;                    // NB+1
    uint_t* binned = (uint_t*)z1b;              // E * 4B

    const int* srcp = ei;
    const int* dstp = ei + E;

    const int G1 = (N + 63) / 64;               // total gemm1 blocks (1563)
    const int G1A = G1 * 1 / 3;
    const int G1B = G1 * 1 / 3;
    const int G1C = G1 - G1A - G1B;

    k_fuseA<<<NBLK + G1A, 256, 0, stream>>>(dstp, bh, E, NB, NBLK,
            x, W1, attS1, attD1, h1b, as1, ad1, N);
    k_fuseB<<<NB + G1B, 256, 0, stream>>>(bh, btot, NBLK, NB, G1A,
            x, W1, attS1, attD1, h1b, as1, ad1, N);
    k_scanT<<<1, 256, 0, stream>>>(btot, bstart, NB);
    k_fuseC<<<NBLK + G1C, 256, 0, stream>>>(srcp, dstp, bh, bstart, binned,
            E, NB, NBLK, G1A + G1B, x, W1, attS1, attD1, h1b, as1, ad1, N);
    k_bucket<<<NB, 256, 0, stream>>>(binned, bstart, rp, col, E, N, NB);

    k_agg1<<<(N + 7) / 8, 256, 0, stream>>>(rp, col, h1b, as1, ad1, b1, z1b, N);
    k_gemm2<<<N / 16, 256, 0, stream>>>(z1b, W2, attS2, attD2, h2b, as2, ad2);
    k_agg2<<<(N + 7) / 8, 256, 0, stream>>>(rp, col, h2b, as2, ad2, b2, out, N);
}